// Round 6
// baseline (367.288 us; speedup 1.0000x reference)
//
#include <hip/hip_runtime.h>
#include <float.h>

#define NV 4096
#define OSTRIDE 451
#define NT 256
typedef unsigned long long u64;

// key = (float-bits(d2) << 32) | idx. d2 >= 0 so float bits are monotone in
// value -> u64 compare == exact lexicographic (d2, idx) compare == top_k's
// stable tie semantics. Partition-invariant under merges.
__device__ __forceinline__ u64 packkey(float d, int idx) {
    return ((u64)__float_as_uint(d) << 32) | (u64)(unsigned)idx;
}

__device__ __forceinline__ void cswap(u64& a, u64& b) {
    bool c = a < b;
    u64 lo = c ? a : b;
    u64 hi = c ? b : a;
    a = lo; b = hi;
}

// sorted ascending insert of ck (caller guarantees ck < k[7]); drops k[7]
__device__ __forceinline__ void ins8(u64 (&k)[8], u64 ck) {
    bool b[7];
#pragma unroll
    for (int q = 0; q < 7; ++q) b[q] = ck < k[q];
#pragma unroll
    for (int q = 7; q >= 1; --q) {
        bool hi = (q == 7) ? true : b[q];
        k[q] = b[q-1] ? k[q-1] : (hi ? ck : k[q]);
    }
    k[0] = b[0] ? ck : k[0];
}

// wave-uniform event loop: pull flagged lanes' candidates, exact u64 check
__device__ __forceinline__ void handle_mask(u64 mask, float dj, int jj, int ob,
                                            int base, u64 (&k)[8], float& T) {
    while (mask) {
        int l = __builtin_ctzll(mask);
        mask &= mask - 1;
        int off = 4*l + jj;
        if (ob == 0 && off < 8) continue;          // seed points already in list
        float cd = __uint_as_float(__builtin_amdgcn_readlane(__float_as_uint(dj), l));
        u64 ck = packkey(cd, base + ob + off);
        if (ck < k[7]) {
            ins8(k, ck);
            T = __uint_as_float((unsigned)(k[7] >> 32));
        }
    }
}

// weight: reference recomputes dist2 from vec = nbr - vert, numpy op order
// (round products, sequential add, no fma), w = 1/(1+dist2)
template<int M>
__device__ __forceinline__ float wcalc(const float* __restrict__ pc, int m,
                                       float vx, float vy, float vz) {
    float qx = pc[m], qy = pc[M+m], qz = pc[2*M+m];
    float dx = __fsub_rn(qx, vx), dy = __fsub_rn(qy, vy), dz = __fsub_rn(qz, vz);
    float dist2 = __fadd_rn(__fadd_rn(__fmul_rn(dx,dx), __fmul_rn(dy,dy)),
                            __fmul_rn(dz,dz));
    return __fdiv_rn(1.0f, __fadd_rn(1.0f, dist2));
}

// feature mean: out[n, COFF+f] = 0.125 * sum_k w_k * feat[idx_k, f]
template<int M, int DF, int COFF, bool TR>
__device__ __forceinline__ void emit(const float* __restrict__ feat,
                                     const float* __restrict__ featT,
                                     float* __restrict__ out, int n, int lane,
                                     const int (&m8)[8], const float (&w8)[8]) {
    for (int f = lane; f < DF; f += 64) {
        float e[8];
#pragma unroll
        for (int k = 0; k < 8; ++k) {
            float fv = TR ? featT[m8[k]*DF + f] : feat[f*M + m8[k]];
            e[k] = __fmul_rn(w8[k], fv);
        }
        float s = __fadd_rn(__fadd_rn(__fadd_rn(e[0],e[1]), __fadd_rn(e[2],e[3])),
                            __fadd_rn(__fadd_rn(e[4],e[5]), __fadd_rn(e[6],e[7])));
        out[n*OSTRIDE + COFF + f] = __fmul_rn(0.125f, s);
    }
}

struct SMem {
    u64   keys[8][4][8];   // [vert_in_blk][part][slot]  2 KiB
    int   idx[8][8];
    float w  [8][8];
};

// One wave owns 4 consecutive vertices and scans PPTS = M/PARTS points
// (part = wave's slice). Lanes process 4 consecutive points each per
// 256-point batch (3 float4 loads). Top-8 lists are wave-uniform u64 keys;
// all branches wave-uniform -> zero divergence tax. Selection distance =
// direct form (p-v).(p-v): abs err ~ulp(d2), ~500x tighter than the
// reference's cancellation form -> matches the f64-arbiter ordering.
template<int M, int DF, int COFF, int PARTS, bool TR>
__device__ __forceinline__ void stage_wave(
    const float* __restrict__ verts,
    const float* __restrict__ pc,     // [3*M]
    const float* __restrict__ feat,   // [DF*M] (fallback gather)
    const float* __restrict__ featT,  // [M*DF] (transposed gather)
    float* __restrict__ out,
    int blk_vbase, SMem& sm)
{
    constexpr int NVB  = 16 / PARTS;     // vertices per block
    constexpr int PPTS = M / PARTS;      // points per wave = 8192 everywhere
    const int tid  = threadIdx.x;
    const int wv   = tid >> 6;
    const int lane = tid & 63;
    const int vg   = wv / PARTS;         // vertex-group within block
    const int part = wv % PARTS;
    const int vbase = blk_vbase + vg*4;
    const int base  = part * PPTS;

    float vx[4], vy[4], vz[4];
#pragma unroll
    for (int u = 0; u < 4; ++u) {
        vx[u] = verts[(vbase+u)*3+0];
        vy[u] = verts[(vbase+u)*3+1];
        vz[u] = verts[(vbase+u)*3+2];
    }

    // seed: exact keys of this part's first 8 points, sorted (19-comparator)
    u64 kk[4][8];
    {
        float sx[8], sy[8], sz[8];
#pragma unroll
        for (int q = 0; q < 8; ++q) {
            sx[q] = pc[base+q]; sy[q] = pc[M+base+q]; sz[q] = pc[2*M+base+q];
        }
#pragma unroll
        for (int u = 0; u < 4; ++u) {
#pragma unroll
            for (int q = 0; q < 8; ++q) {
                float dx=__fsub_rn(sx[q],vx[u]), dy=__fsub_rn(sy[q],vy[u]), dz=__fsub_rn(sz[q],vz[u]);
                float d = __fmaf_rn(dz,dz,__fmaf_rn(dy,dy,__fmul_rn(dx,dx)));
                kk[u][q] = packkey(d, base + q);
            }
            cswap(kk[u][0],kk[u][1]); cswap(kk[u][2],kk[u][3]); cswap(kk[u][4],kk[u][5]); cswap(kk[u][6],kk[u][7]);
            cswap(kk[u][0],kk[u][2]); cswap(kk[u][1],kk[u][3]); cswap(kk[u][4],kk[u][6]); cswap(kk[u][5],kk[u][7]);
            cswap(kk[u][1],kk[u][2]); cswap(kk[u][5],kk[u][6]);
            cswap(kk[u][0],kk[u][4]); cswap(kk[u][1],kk[u][5]); cswap(kk[u][2],kk[u][6]); cswap(kk[u][3],kk[u][7]);
            cswap(kk[u][2],kk[u][4]); cswap(kk[u][3],kk[u][5]);
            cswap(kk[u][1],kk[u][2]); cswap(kk[u][3],kk[u][4]); cswap(kk[u][5],kk[u][6]);
        }
    }
    float T[4];
#pragma unroll
    for (int u = 0; u < 4; ++u) T[u] = __uint_as_float((unsigned)(kk[u][7] >> 32));

    const float* __restrict__ px = pc + base;
    const float* __restrict__ py = pc + M + base;
    const float* __restrict__ pz = pc + 2*M + base;

    // 256-pt batches: lane handles points 4*lane..4*lane+3; 1-deep prefetch
    float4 X = *(const float4*)(px + 4*lane);
    float4 Y = *(const float4*)(py + 4*lane);
    float4 Z = *(const float4*)(pz + 4*lane);
    for (int ob = 0; ob < PPTS; ob += 256) {
        int nb = (ob + 256 < PPTS) ? ob + 256 : 0;   // last prefetch dead
        float4 nX = *(const float4*)(px + nb + 4*lane);
        float4 nY = *(const float4*)(py + nb + 4*lane);
        float4 nZ = *(const float4*)(pz + nb + 4*lane);
#pragma unroll
        for (int u = 0; u < 4; ++u) {
            float dx0=__fsub_rn(X.x,vx[u]), dy0=__fsub_rn(Y.x,vy[u]), dz0=__fsub_rn(Z.x,vz[u]);
            float dx1=__fsub_rn(X.y,vx[u]), dy1=__fsub_rn(Y.y,vy[u]), dz1=__fsub_rn(Z.y,vz[u]);
            float dx2=__fsub_rn(X.z,vx[u]), dy2=__fsub_rn(Y.z,vy[u]), dz2=__fsub_rn(Z.z,vz[u]);
            float dx3=__fsub_rn(X.w,vx[u]), dy3=__fsub_rn(Y.w,vy[u]), dz3=__fsub_rn(Z.w,vz[u]);
            float d0=__fmaf_rn(dz0,dz0,__fmaf_rn(dy0,dy0,__fmul_rn(dx0,dx0)));
            float d1=__fmaf_rn(dz1,dz1,__fmaf_rn(dy1,dy1,__fmul_rn(dx1,dx1)));
            float d2=__fmaf_rn(dz2,dz2,__fmaf_rn(dy2,dy2,__fmul_rn(dx2,dx2)));
            float d3=__fmaf_rn(dz3,dz3,__fmaf_rn(dy3,dy3,__fmul_rn(dx3,dx3)));
            u64 b0 = __ballot(d0 <= T[u]);
            u64 b1 = __ballot(d1 <= T[u]);
            u64 b2 = __ballot(d2 <= T[u]);
            u64 b3 = __ballot(d3 <= T[u]);
            if (b0 | b1 | b2 | b3) {                 // wave-uniform rare path
                handle_mask(b0, d0, 0, ob, base, kk[u], T[u]);
                handle_mask(b1, d1, 1, ob, base, kk[u], T[u]);
                handle_mask(b2, d2, 2, ob, base, kk[u], T[u]);
                handle_mask(b3, d3, 3, ob, base, kk[u], T[u]);
            }
        }
        X = nX; Y = nY; Z = nZ;
    }

    if (PARTS == 1) {
        // wave finishes its 4 vertices directly (no LDS, no barriers)
#pragma unroll
        for (int u = 0; u < 4; ++u) {
            int m8[8]; float w8[8];
#pragma unroll
            for (int k = 0; k < 8; ++k) {
                int m = (int)(kk[u][k] & 0xFFFFFFFFu);
                m8[k] = m;
                w8[k] = wcalc<M>(pc, m, vx[u], vy[u], vz[u]);
            }
            emit<M, DF, COFF, TR>(feat, featT, out, vbase+u, lane, m8, w8);
        }
    } else {
        if (lane == 0) {
#pragma unroll
            for (int u = 0; u < 4; ++u)
#pragma unroll
                for (int q = 0; q < 8; ++q)
                    sm.keys[vg*4+u][part][q] = kk[u][q];
        }
        __syncthreads();
        if (tid < NVB) {     // thread t: merge PARTS sorted lists of vertex t
            u64 cur[8];
#pragma unroll
            for (int q = 0; q < 8; ++q) cur[q] = ~0ull;
            for (int p = 0; p < PARTS; ++p) {
#pragma unroll 1
                for (int s = 0; s < 8; ++s) {
                    u64 ck = sm.keys[tid][p][s];
                    if (ck >= cur[7]) break;        // lists sorted -> safe
                    ins8(cur, ck);
                }
            }
            int n = blk_vbase + tid;
            float wx = verts[n*3], wy = verts[n*3+1], wz = verts[n*3+2];
#pragma unroll
            for (int k = 0; k < 8; ++k) {
                int m = (int)(cur[k] & 0xFFFFFFFFu);
                sm.idx[tid][k] = m;
                sm.w  [tid][k] = wcalc<M>(pc, m, wx, wy, wz);
            }
        }
        __syncthreads();
        constexpr int VW = NVB / 4;                  // verts gathered per wave
#pragma unroll
        for (int vv = 0; vv < VW; ++vv) {
            int v = wv*VW + vv;
            int m8[8]; float w8[8];
#pragma unroll
            for (int k = 0; k < 8; ++k) { m8[k] = sm.idx[v][k]; w8[k] = sm.w[v][k]; }
            emit<M, DF, COFF, TR>(feat, featT, out, blk_vbase + v, lane, m8, w8);
        }
    }
}

// fused transpose: feat [Df, M] -> featT [M, Df]; coalesced reads, 16B writes.
__global__ __launch_bounds__(256)
void tr_kernel(const float* __restrict__ f1, const float* __restrict__ f2,
               const float* __restrict__ f3, float* __restrict__ ws)
{
    int b = blockIdx.x;
    const float* src; float* dst; int M, LOGM, DF;
    int g;
    if (b < 2048)      { src = f1; dst = ws;           M = 32768; LOGM = 15; DF = 64;  g = b*256 + threadIdx.x; }
    else if (b < 4096) { src = f2; dst = ws + 2097152; M = 16384; LOGM = 14; DF = 128; g = (b-2048)*256 + threadIdx.x; }
    else               { src = f3; dst = ws + 4194304; M = 8192;  LOGM = 13; DF = 256; g = (b-4096)*256 + threadIdx.x; }
    int m  = g & (M - 1);
    int f4 = g >> LOGM;           // f4 < DF/4
    float4 r;
    r.x = src[(4*f4+0)*M + m];
    r.y = src[(4*f4+1)*M + m];
    r.z = src[(4*f4+2)*M + m];
    r.w = src[(4*f4+3)*M + m];
    *(float4*)&dst[m*DF + 4*f4] = r;
}

// Grid: 1024 stage1 blocks (4 verts, 4 parts) + 512 stage2 (8 verts, 2 parts)
// + 256 stage3 (16 verts, 1 part) + 1 copy block. Every scan wave = 8192 pts.
template<bool TR>
__global__ __launch_bounds__(NT, 4)
void gp_kernel(const float* __restrict__ verts,
               const float* __restrict__ pc1, const float* __restrict__ f1,
               const float* __restrict__ pc2, const float* __restrict__ f2,
               const float* __restrict__ pc3, const float* __restrict__ f3,
               const float* __restrict__ ws,
               float* __restrict__ out)
{
    __shared__ SMem sm;
    int b = blockIdx.x;
    if (b < 1024) {
        stage_wave<32768,  64,   3, 4, TR>(verts, pc1, f1, ws,           out, b*4, sm);
    } else if (b < 1536) {
        stage_wave<16384, 128,  67, 2, TR>(verts, pc2, f2, ws + 2097152, out, (b-1024)*8, sm);
    } else if (b < 1792) {
        stage_wave< 8192, 256, 195, 1, TR>(verts, pc3, f3, ws + 4194304, out, (b-1536)*16, sm);
    } else {
        for (int i = threadIdx.x; i < NV*3; i += NT)
            out[(i/3)*OSTRIDE + (i % 3)] = verts[i];
    }
}

extern "C" void kernel_launch(void* const* d_in, const int* in_sizes, int n_in,
                              void* d_out, int out_size, void* d_ws, size_t ws_size,
                              hipStream_t stream) {
    const float* verts = (const float*)d_in[0];
    // d_in[1] = pc0_coords: unused (reference discards stage 0)
    const float* pc1 = (const float*)d_in[2];
    const float* f1  = (const float*)d_in[3];
    const float* pc2 = (const float*)d_in[4];
    const float* f2  = (const float*)d_in[5];
    const float* pc3 = (const float*)d_in[6];
    const float* f3  = (const float*)d_in[7];
    float* out = (float*)d_out;
    float* ws  = (float*)d_ws;

    if (ws_size >= 6291456u * sizeof(float)) {
        tr_kernel<<<6144, 256, 0, stream>>>(f1, f2, f3, ws);
        gp_kernel<true><<<1793, NT, 0, stream>>>(verts, pc1, f1, pc2, f2, pc3, f3, ws, out);
    } else {
        gp_kernel<false><<<1793, NT, 0, stream>>>(verts, pc1, f1, pc2, f2, pc3, f3, ws, out);
    }
}

// Round 7
// 305.531 us; speedup vs baseline: 1.2021x; 1.2021x over previous
//
#include <hip/hip_runtime.h>
#include <float.h>

#define NV 4096
#define OSTRIDE 451
#define NT 256
typedef unsigned long long u64;

// key = (float-bits(d2) << 32) | idx. d2 >= 0 so float bits are monotone in
// value -> u64 compare == exact lexicographic (d2, idx) compare == top_k's
// stable tie semantics.
__device__ __forceinline__ u64 packkey(float d, int idx) {
    return ((u64)__float_as_uint(d) << 32) | (u64)(unsigned)idx;
}

__device__ __forceinline__ void cswap(u64& a, u64& b) {
    bool c = a < b;
    u64 lo = c ? a : b;
    u64 hi = c ? b : a;
    a = lo; b = hi;
}

// sorted ascending insert of ck (caller guarantees ck < k[7]); drops k[7]
__device__ __forceinline__ void ins8(u64 (&k)[8], u64 ck) {
    bool b[7];
#pragma unroll
    for (int q = 0; q < 7; ++q) b[q] = ck < k[q];
#pragma unroll
    for (int q = 7; q >= 1; --q) {
        bool hi = (q == 7) ? true : b[q];
        k[q] = b[q-1] ? k[q-1] : (hi ? ck : k[q]);
    }
    k[0] = b[0] ? ck : k[0];
}

// wave-uniform event loop with post-insert refilter (prunes seed storms)
__device__ __forceinline__ void handle8(u64 mask, float dj, int jj, int ob,
                                        u64 (&k)[8], float& T) {
    while (mask) {
        int l = __builtin_ctzll(mask);
        mask &= mask - 1;
        int cm = ob + 8*l + jj;
        if (cm < 8) continue;                      // seed points already in list
        float cd = __uint_as_float(__builtin_amdgcn_readlane(__float_as_uint(dj), l));
        u64 ck = packkey(cd, cm);
        if (ck < k[7]) {
            ins8(k, ck);
            T = __uint_as_float((unsigned)(k[7] >> 32));
            mask &= __ballot(dj <= T);             // refilter vs tightened T
        }
    }
}

// weight: reference recomputes dist2 from vec = nbr - vert, numpy op order
// (round products, sequential add, no fma), w = 1/(1+dist2)
template<int M>
__device__ __forceinline__ float wcalc(const float* __restrict__ pc, int m,
                                       float vx, float vy, float vz) {
    float qx = pc[m], qy = pc[M+m], qz = pc[2*M+m];
    float dx = __fsub_rn(qx, vx), dy = __fsub_rn(qy, vy), dz = __fsub_rn(qz, vz);
    float dist2 = __fadd_rn(__fadd_rn(__fmul_rn(dx,dx), __fmul_rn(dy,dy)),
                            __fmul_rn(dz,dz));
    return __fdiv_rn(1.0f, __fadd_rn(1.0f, dist2));
}

// One wave, 2 vertices, full scan of one stage (PARTS=1: minimal events, no
// merges, no LDS, no barriers). Lanes process 8 consecutive points per
// 512-point batch (6 float4 loads, 1-deep prefetch). Top-8 = wave-uniform
// u64 keys; all branches wave-uniform. Selection distance = direct form
// (p-v).(p-v): abs err ~ulp(d2), ~500x tighter than the reference's
// cancellation form -> matches the f64-arbiter ordering.
template<int M, int DF, int COFF, bool TR>
__device__ __forceinline__ void stage2v(
    const float* __restrict__ verts,
    const float* __restrict__ pc,     // [3*M]
    const float* __restrict__ feat,   // [DF*M] (fallback gather)
    const float* __restrict__ featT,  // [M*DF] (transposed gather)
    float* __restrict__ out,
    int vbase, int lane)
{
    float vx[2], vy[2], vz[2];
#pragma unroll
    for (int u = 0; u < 2; ++u) {
        vx[u] = verts[(vbase+u)*3+0];
        vy[u] = verts[(vbase+u)*3+1];
        vz[u] = verts[(vbase+u)*3+2];
    }

    // seed: exact keys of points 0..7, sorted (Batcher 19-comparator network)
    u64 kk[2][8];
    {
        float sx[8], sy[8], sz[8];
#pragma unroll
        for (int q = 0; q < 8; ++q) { sx[q]=pc[q]; sy[q]=pc[M+q]; sz[q]=pc[2*M+q]; }
#pragma unroll
        for (int u = 0; u < 2; ++u) {
#pragma unroll
            for (int q = 0; q < 8; ++q) {
                float dx=__fsub_rn(sx[q],vx[u]), dy=__fsub_rn(sy[q],vy[u]), dz=__fsub_rn(sz[q],vz[u]);
                float d = __fmaf_rn(dz,dz,__fmaf_rn(dy,dy,__fmul_rn(dx,dx)));
                kk[u][q] = packkey(d, q);
            }
            cswap(kk[u][0],kk[u][1]); cswap(kk[u][2],kk[u][3]); cswap(kk[u][4],kk[u][5]); cswap(kk[u][6],kk[u][7]);
            cswap(kk[u][0],kk[u][2]); cswap(kk[u][1],kk[u][3]); cswap(kk[u][4],kk[u][6]); cswap(kk[u][5],kk[u][7]);
            cswap(kk[u][1],kk[u][2]); cswap(kk[u][5],kk[u][6]);
            cswap(kk[u][0],kk[u][4]); cswap(kk[u][1],kk[u][5]); cswap(kk[u][2],kk[u][6]); cswap(kk[u][3],kk[u][7]);
            cswap(kk[u][2],kk[u][4]); cswap(kk[u][3],kk[u][5]);
            cswap(kk[u][1],kk[u][2]); cswap(kk[u][3],kk[u][4]); cswap(kk[u][5],kk[u][6]);
        }
    }
    float T[2];
#pragma unroll
    for (int u = 0; u < 2; ++u) T[u] = __uint_as_float((unsigned)(kk[u][7] >> 32));

    const float* __restrict__ px = pc;
    const float* __restrict__ py = pc + M;
    const float* __restrict__ pz = pc + 2*M;

    // 512-pt batches: lane owns points 8*lane .. 8*lane+7
    float4 Xa = *(const float4*)(px + 8*lane), Xb = *(const float4*)(px + 8*lane + 4);
    float4 Ya = *(const float4*)(py + 8*lane), Yb = *(const float4*)(py + 8*lane + 4);
    float4 Za = *(const float4*)(pz + 8*lane), Zb = *(const float4*)(pz + 8*lane + 4);
    for (int ob = 0; ob < M; ob += 512) {
        int nb = (ob + 512 < M) ? ob + 512 : 0;     // last prefetch dead
        float4 nXa = *(const float4*)(px + nb + 8*lane), nXb = *(const float4*)(px + nb + 8*lane + 4);
        float4 nYa = *(const float4*)(py + nb + 8*lane), nYb = *(const float4*)(py + nb + 8*lane + 4);
        float4 nZa = *(const float4*)(pz + nb + 8*lane), nZb = *(const float4*)(pz + nb + 8*lane + 4);
        float xs[8] = {Xa.x,Xa.y,Xa.z,Xa.w,Xb.x,Xb.y,Xb.z,Xb.w};
        float ys[8] = {Ya.x,Ya.y,Ya.z,Ya.w,Yb.x,Yb.y,Yb.z,Yb.w};
        float zs[8] = {Za.x,Za.y,Za.z,Za.w,Zb.x,Zb.y,Zb.z,Zb.w};
#pragma unroll
        for (int u = 0; u < 2; ++u) {
            float d[8];
#pragma unroll
            for (int j = 0; j < 8; ++j) {
                float dx = __fsub_rn(xs[j], vx[u]);
                float dy = __fsub_rn(ys[j], vy[u]);
                float dz = __fsub_rn(zs[j], vz[u]);
                d[j] = __fmaf_rn(dz,dz,__fmaf_rn(dy,dy,__fmul_rn(dx,dx)));
            }
            u64 mm[8]; u64 any = 0;
#pragma unroll
            for (int j = 0; j < 8; ++j) { mm[j] = __ballot(d[j] <= T[u]); any |= mm[j]; }
            if (any) {                              // wave-uniform rare path
#pragma unroll
                for (int j = 0; j < 8; ++j) handle8(mm[j], d[j], j, ob, kk[u], T[u]);
            }
        }
        Xa = nXa; Xb = nXb; Ya = nYa; Yb = nYb; Za = nZa; Zb = nZb;
    }

    // weights + feature mean, wave-local (no LDS)
#pragma unroll
    for (int u = 0; u < 2; ++u) {
        int m8[8]; float w8[8];
#pragma unroll
        for (int k = 0; k < 8; ++k) {
            int m = (int)(kk[u][k] & 0xFFFFFFFFu);
            m8[k] = m;
            w8[k] = wcalc<M>(pc, m, vx[u], vy[u], vz[u]);
        }
        const int n = vbase + u;
        for (int f = lane; f < DF; f += 64) {
            float e[8];
#pragma unroll
            for (int k = 0; k < 8; ++k) {
                float fv = TR ? featT[m8[k]*DF + f] : feat[f*M + m8[k]];
                e[k] = __fmul_rn(w8[k], fv);
            }
            float s = __fadd_rn(__fadd_rn(__fadd_rn(e[0],e[1]), __fadd_rn(e[2],e[3])),
                                __fadd_rn(__fadd_rn(e[4],e[5]), __fadd_rn(e[6],e[7])));
            out[n*OSTRIDE + COFF + f] = __fmul_rn(0.125f, s);
        }
    }
}

// LDS-tiled transpose: feat [Df, M] -> featT [M, Df]; BOTH sides coalesced.
// 64x64 tiles; 1536 blocks total (512 per stage).
__global__ __launch_bounds__(256)
void tr_kernel(const float* __restrict__ f1, const float* __restrict__ f2,
               const float* __restrict__ f3, float* __restrict__ ws)
{
    __shared__ float s[64][65];
    int b = blockIdx.x;
    const float* src; float* dst; int M, DF, tm, tf;
    if (b < 512)       { src = f1; dst = ws;           M = 32768; DF = 64;  tm = b & 511;        tf = b >> 9; }
    else if (b < 1024) { src = f2; dst = ws + 2097152; M = 16384; DF = 128; tm = (b-512) & 255;  tf = (b-512) >> 8; }
    else               { src = f3; dst = ws + 4194304; M = 8192;  DF = 256; tm = (b-1024) & 127; tf = (b-1024) >> 7; }
    const int mb = tm*64, fb = tf*64;
    const int tid = threadIdx.x;
    const int a0 = tid & 63, a1 = tid >> 6;
#pragma unroll
    for (int i = 0; i < 16; ++i) {                  // read: lanes along m
        int ff = a1 + i*4;
        s[ff][a0] = src[(fb+ff)*M + mb + a0];
    }
    __syncthreads();
#pragma unroll
    for (int i = 0; i < 16; ++i) {                  // write: lanes along f
        int mm2 = a1 + i*4;
        dst[(mb+mm2)*DF + fb + a0] = s[a0][mm2];
    }
}

// Grid: 512 scan blocks (4 waves x 2 verts, each wave runs all 3 stages
// sequentially -> every wave identical: 114688 pairs) + 1 coord-copy block.
template<bool TR>
__global__ __launch_bounds__(NT, 2)
void gp_kernel(const float* __restrict__ verts,
               const float* __restrict__ pc1, const float* __restrict__ f1,
               const float* __restrict__ pc2, const float* __restrict__ f2,
               const float* __restrict__ pc3, const float* __restrict__ f3,
               const float* __restrict__ ws,
               float* __restrict__ out)
{
    int b = blockIdx.x;
    if (b < 512) {
        const int lane = threadIdx.x & 63;
        const int wv   = threadIdx.x >> 6;
        const int vbase = b*8 + wv*2;
        stage2v<32768,  64,   3, TR>(verts, pc1, f1, ws,           out, vbase, lane);
        stage2v<16384, 128,  67, TR>(verts, pc2, f2, ws + 2097152, out, vbase, lane);
        stage2v< 8192, 256, 195, TR>(verts, pc3, f3, ws + 4194304, out, vbase, lane);
    } else {
        for (int i = threadIdx.x; i < NV*3; i += NT)
            out[(i/3)*OSTRIDE + (i % 3)] = verts[i];
    }
}

extern "C" void kernel_launch(void* const* d_in, const int* in_sizes, int n_in,
                              void* d_out, int out_size, void* d_ws, size_t ws_size,
                              hipStream_t stream) {
    const float* verts = (const float*)d_in[0];
    // d_in[1] = pc0_coords: unused (reference discards stage 0)
    const float* pc1 = (const float*)d_in[2];
    const float* f1  = (const float*)d_in[3];
    const float* pc2 = (const float*)d_in[4];
    const float* f2  = (const float*)d_in[5];
    const float* pc3 = (const float*)d_in[6];
    const float* f3  = (const float*)d_in[7];
    float* out = (float*)d_out;
    float* ws  = (float*)d_ws;

    if (ws_size >= 6291456u * sizeof(float)) {
        tr_kernel<<<1536, 256, 0, stream>>>(f1, f2, f3, ws);
        gp_kernel<true><<<513, NT, 0, stream>>>(verts, pc1, f1, pc2, f2, pc3, f3, ws, out);
    } else {
        gp_kernel<false><<<513, NT, 0, stream>>>(verts, pc1, f1, pc2, f2, pc3, f3, ws, out);
    }
}

// Round 8
// 242.737 us; speedup vs baseline: 1.5131x; 1.2587x over previous
//
#include <hip/hip_runtime.h>
#include <float.h>

#define NV 4096
#define OSTRIDE 451
#define NT 256
typedef unsigned long long u64;

// key = (float-bits(d2) << 32) | idx. d2 >= 0 so float bits are monotone in
// value -> u64 compare == exact lexicographic (d2, idx) compare == top_k's
// stable tie semantics.
__device__ __forceinline__ u64 packkey(float d, int idx) {
    return ((u64)__float_as_uint(d) << 32) | (u64)(unsigned)idx;
}

__device__ __forceinline__ void cswap(u64& a, u64& b) {
    bool c = a < b;
    u64 lo = c ? a : b;
    u64 hi = c ? b : a;
    a = lo; b = hi;
}

// sorted ascending insert of ck (caller guarantees ck < k[7]); drops k[7]
__device__ __forceinline__ void ins8(u64 (&k)[8], u64 ck) {
    bool b[7];
#pragma unroll
    for (int q = 0; q < 7; ++q) b[q] = ck < k[q];
#pragma unroll
    for (int q = 7; q >= 1; --q) {
        bool hi = (q == 7) ? true : b[q];
        k[q] = b[q-1] ? k[q-1] : (hi ? ck : k[q]);
    }
    k[0] = b[0] ? ck : k[0];
}

// wave-uniform event loop with post-insert refilter (prunes seed storms)
__device__ __forceinline__ void handle8(u64 mask, float dj, int jj, int ob,
                                        u64 (&k)[8], float& T) {
    while (mask) {
        int l = __builtin_ctzll(mask);
        mask &= mask - 1;
        int cm = ob + 8*l + jj;
        if (cm < 8) continue;                      // seed points already in list
        float cd = __uint_as_float(__builtin_amdgcn_readlane(__float_as_uint(dj), l));
        u64 ck = packkey(cd, cm);
        if (ck < k[7]) {
            ins8(k, ck);
            T = __uint_as_float((unsigned)(k[7] >> 32));
            mask &= __ballot(dj <= T);             // refilter vs tightened T
        }
    }
}

// weight: reference recomputes dist2 from vec = nbr - vert, numpy op order
// (round products, sequential add, no fma), w = 1/(1+dist2)
template<int M>
__device__ __forceinline__ float wcalc(const float* __restrict__ pc, int m,
                                       float vx, float vy, float vz) {
    float qx = pc[m], qy = pc[M+m], qz = pc[2*M+m];
    float dx = __fsub_rn(qx, vx), dy = __fsub_rn(qy, vy), dz = __fsub_rn(qz, vz);
    float dist2 = __fadd_rn(__fadd_rn(__fmul_rn(dx,dx), __fmul_rn(dy,dy)),
                            __fmul_rn(dz,dz));
    return __fdiv_rn(1.0f, __fadd_rn(1.0f, dist2));
}

// One wave, ONE vertex, full scan of one stage (PARTS=1: minimal events, no
// merges, no LDS, no barriers; U=1: max wave count = 4096 identical waves).
// Lanes process 8 consecutive points per 512-point batch (6 float4 loads,
// 1-deep prefetch). Top-8 = wave-uniform u64 keys; all branches wave-uniform.
// Selection distance = direct form (p-v).(p-v): abs err ~ulp(d2), ~500x
// tighter than the reference's cancellation form -> matches the f64-arbiter
// ordering.
template<int M, int DF, int COFF, bool TR>
__device__ __forceinline__ void stage1v(
    const float* __restrict__ verts,
    const float* __restrict__ pc,     // [3*M]
    const float* __restrict__ feat,   // [DF*M] (fallback gather)
    const float* __restrict__ featT,  // [M*DF] (transposed gather)
    float* __restrict__ out,
    int n, int lane)
{
    const float vx = verts[n*3+0], vy = verts[n*3+1], vz = verts[n*3+2];

    // seed: exact keys of points 0..7, sorted (Batcher 19-comparator network)
    u64 kk[8];
    {
#pragma unroll
        for (int q = 0; q < 8; ++q) {
            float dx=__fsub_rn(pc[q],vx), dy=__fsub_rn(pc[M+q],vy), dz=__fsub_rn(pc[2*M+q],vz);
            float d = __fmaf_rn(dz,dz,__fmaf_rn(dy,dy,__fmul_rn(dx,dx)));
            kk[q] = packkey(d, q);
        }
        cswap(kk[0],kk[1]); cswap(kk[2],kk[3]); cswap(kk[4],kk[5]); cswap(kk[6],kk[7]);
        cswap(kk[0],kk[2]); cswap(kk[1],kk[3]); cswap(kk[4],kk[6]); cswap(kk[5],kk[7]);
        cswap(kk[1],kk[2]); cswap(kk[5],kk[6]);
        cswap(kk[0],kk[4]); cswap(kk[1],kk[5]); cswap(kk[2],kk[6]); cswap(kk[3],kk[7]);
        cswap(kk[2],kk[4]); cswap(kk[3],kk[5]);
        cswap(kk[1],kk[2]); cswap(kk[3],kk[4]); cswap(kk[5],kk[6]);
    }
    float T = __uint_as_float((unsigned)(kk[7] >> 32));

    const float* __restrict__ px = pc;
    const float* __restrict__ py = pc + M;
    const float* __restrict__ pz = pc + 2*M;

    // 512-pt batches: lane owns points 8*lane .. 8*lane+7
    float4 Xa = *(const float4*)(px + 8*lane), Xb = *(const float4*)(px + 8*lane + 4);
    float4 Ya = *(const float4*)(py + 8*lane), Yb = *(const float4*)(py + 8*lane + 4);
    float4 Za = *(const float4*)(pz + 8*lane), Zb = *(const float4*)(pz + 8*lane + 4);
    for (int ob = 0; ob < M; ob += 512) {
        int nb = (ob + 512 < M) ? ob + 512 : 0;     // last prefetch dead
        float4 nXa = *(const float4*)(px + nb + 8*lane), nXb = *(const float4*)(px + nb + 8*lane + 4);
        float4 nYa = *(const float4*)(py + nb + 8*lane), nYb = *(const float4*)(py + nb + 8*lane + 4);
        float4 nZa = *(const float4*)(pz + nb + 8*lane), nZb = *(const float4*)(pz + nb + 8*lane + 4);
        float xs[8] = {Xa.x,Xa.y,Xa.z,Xa.w,Xb.x,Xb.y,Xb.z,Xb.w};
        float ys[8] = {Ya.x,Ya.y,Ya.z,Ya.w,Yb.x,Yb.y,Yb.z,Yb.w};
        float zs[8] = {Za.x,Za.y,Za.z,Za.w,Zb.x,Zb.y,Zb.z,Zb.w};
        float d[8];
#pragma unroll
        for (int j = 0; j < 8; ++j) {
            float dx = __fsub_rn(xs[j], vx);
            float dy = __fsub_rn(ys[j], vy);
            float dz = __fsub_rn(zs[j], vz);
            d[j] = __fmaf_rn(dz,dz,__fmaf_rn(dy,dy,__fmul_rn(dx,dx)));
        }
        u64 mm[8]; u64 any = 0;
#pragma unroll
        for (int j = 0; j < 8; ++j) { mm[j] = __ballot(d[j] <= T); any |= mm[j]; }
        if (any) {                                  // wave-uniform rare path
#pragma unroll
            for (int j = 0; j < 8; ++j) handle8(mm[j], d[j], j, ob, kk, T);
        }
        Xa = nXa; Xb = nXb; Ya = nYa; Yb = nYb; Za = nZa; Zb = nZb;
    }

    // weights + feature mean, wave-local (no LDS)
    int m8[8]; float w8[8];
#pragma unroll
    for (int k = 0; k < 8; ++k) {
        int m = (int)(kk[k] & 0xFFFFFFFFu);
        m8[k] = m;
        w8[k] = wcalc<M>(pc, m, vx, vy, vz);
    }
    for (int f = lane; f < DF; f += 64) {
        float e[8];
#pragma unroll
        for (int k = 0; k < 8; ++k) {
            float fv = TR ? featT[m8[k]*DF + f] : feat[f*M + m8[k]];
            e[k] = __fmul_rn(w8[k], fv);
        }
        float s = __fadd_rn(__fadd_rn(__fadd_rn(e[0],e[1]), __fadd_rn(e[2],e[3])),
                            __fadd_rn(__fadd_rn(e[4],e[5]), __fadd_rn(e[6],e[7])));
        out[n*OSTRIDE + COFF + f] = __fmul_rn(0.125f, s);
    }
}

// LDS-tiled transpose: feat [Df, M] -> featT [M, Df]; BOTH sides coalesced.
// 64x64 tiles; 1536 blocks total (512 per stage).
__global__ __launch_bounds__(256)
void tr_kernel(const float* __restrict__ f1, const float* __restrict__ f2,
               const float* __restrict__ f3, float* __restrict__ ws)
{
    __shared__ float s[64][65];
    int b = blockIdx.x;
    const float* src; float* dst; int M, DF, tm, tf;
    if (b < 512)       { src = f1; dst = ws;           M = 32768; DF = 64;  tm = b & 511;        tf = b >> 9; }
    else if (b < 1024) { src = f2; dst = ws + 2097152; M = 16384; DF = 128; tm = (b-512) & 255;  tf = (b-512) >> 8; }
    else               { src = f3; dst = ws + 4194304; M = 8192;  DF = 256; tm = (b-1024) & 127; tf = (b-1024) >> 7; }
    const int mb = tm*64, fb = tf*64;
    const int tid = threadIdx.x;
    const int a0 = tid & 63, a1 = tid >> 6;
#pragma unroll
    for (int i = 0; i < 16; ++i) {                  // read: lanes along m
        int ff = a1 + i*4;
        s[ff][a0] = src[(fb+ff)*M + mb + a0];
    }
    __syncthreads();
#pragma unroll
    for (int i = 0; i < 16; ++i) {                  // write: lanes along f
        int mm2 = a1 + i*4;
        dst[(mb+mm2)*DF + fb + a0] = s[a0][mm2];
    }
}

// Grid: 1024 scan blocks (4 waves x 1 vertex; each wave runs all 3 stages
// sequentially -> 4096 identical waves, 57344 pairs each, zero tail)
// + 1 coord-copy block.
template<bool TR>
__global__ __launch_bounds__(NT, 4)
void gp_kernel(const float* __restrict__ verts,
               const float* __restrict__ pc1, const float* __restrict__ f1,
               const float* __restrict__ pc2, const float* __restrict__ f2,
               const float* __restrict__ pc3, const float* __restrict__ f3,
               const float* __restrict__ ws,
               float* __restrict__ out)
{
    int b = blockIdx.x;
    if (b < 1024) {
        const int lane = threadIdx.x & 63;
        const int wv   = threadIdx.x >> 6;
        const int n = b*4 + wv;
        stage1v<32768,  64,   3, TR>(verts, pc1, f1, ws,           out, n, lane);
        stage1v<16384, 128,  67, TR>(verts, pc2, f2, ws + 2097152, out, n, lane);
        stage1v< 8192, 256, 195, TR>(verts, pc3, f3, ws + 4194304, out, n, lane);
    } else {
        for (int i = threadIdx.x; i < NV*3; i += NT)
            out[(i/3)*OSTRIDE + (i % 3)] = verts[i];
    }
}

extern "C" void kernel_launch(void* const* d_in, const int* in_sizes, int n_in,
                              void* d_out, int out_size, void* d_ws, size_t ws_size,
                              hipStream_t stream) {
    const float* verts = (const float*)d_in[0];
    // d_in[1] = pc0_coords: unused (reference discards stage 0)
    const float* pc1 = (const float*)d_in[2];
    const float* f1  = (const float*)d_in[3];
    const float* pc2 = (const float*)d_in[4];
    const float* f2  = (const float*)d_in[5];
    const float* pc3 = (const float*)d_in[6];
    const float* f3  = (const float*)d_in[7];
    float* out = (float*)d_out;
    float* ws  = (float*)d_ws;

    if (ws_size >= 6291456u * sizeof(float)) {
        tr_kernel<<<1536, 256, 0, stream>>>(f1, f2, f3, ws);
        gp_kernel<true><<<1025, NT, 0, stream>>>(verts, pc1, f1, pc2, f2, pc3, f3, ws, out);
    } else {
        gp_kernel<false><<<1025, NT, 0, stream>>>(verts, pc1, f1, pc2, f2, pc3, f3, ws, out);
    }
}